// Round 1
// baseline (179.812 us; speedup 1.0000x reference)
//
#include <hip/hip_runtime.h>
#include <hip/hip_bf16.h>
#include <stdint.h>

#define N_Q 4096
#define N_K 4096
#define DIM 512

typedef float f32x4 __attribute__((ext_vector_type(4)));
typedef __bf16 bf16x8 __attribute__((ext_vector_type(8)));
typedef unsigned short u16x4 __attribute__((ext_vector_type(4)));

__device__ __forceinline__ f32x4 mfma_bf16(bf16x8 a, bf16x8 b, f32x4 c) {
  return __builtin_amdgcn_mfma_f32_16x16x32_bf16(a, b, c, 0, 0, 0);
}

// Round-to-nearest bf16 (bit pattern), plus exact low残 split: x ~= hi + lo,
// hi = RN(x), lo = trunc_bf16(x - hi). Error ~2^-17 relative.
__device__ __forceinline__ void split4(const f32x4 v, u16x4& h, u16x4& l) {
#pragma unroll
  for (int i = 0; i < 4; ++i) {
    float f = v[i];
    uint32_t u = __builtin_bit_cast(uint32_t, f);
    uint32_t hb = (u + 0x8000u) & 0xffff0000u;   // round-half-up to bf16
    float hf = __builtin_bit_cast(float, hb);
    float lf = f - hf;                            // exact (Sterbenz)
    h[i] = (unsigned short)(hb >> 16);
    l[i] = (unsigned short)(__builtin_bit_cast(uint32_t, lf) >> 16);
  }
}

__device__ __forceinline__ unsigned short bf16r(float f) {
  uint32_t u = __builtin_bit_cast(uint32_t, f);
  return (unsigned short)((u + 0x8000u) >> 16);
}

// ---------------------------------------------------------------------------
// Kernel 1: S = Q * K^T   (bf16x3 split GEMM, fp32 out)
// 128x128 tile, BK=64, 256 threads (4 waves 2x2), each wave 64x64 (4x4 frags)
// ---------------------------------------------------------------------------
__global__ __launch_bounds__(256, 2) void qk_kernel(const float* __restrict__ Q,
                                                    const float* __restrict__ K,
                                                    float* __restrict__ S) {
  __shared__ __align__(16) char sAh[16384];   // 128 x 64 bf16, row stride 128B
  __shared__ __align__(16) char sAl[16384];
  __shared__ __align__(16) char sBh[16384];
  __shared__ __align__(16) char sBl[16384];

  const int tid = threadIdx.x;
  const int rbase = blockIdx.y * 128;   // Q rows
  const int cbase = blockIdx.x * 128;   // K rows (= S cols)
  const int lane = tid & 63, wid = tid >> 6;
  const int wr = wid >> 1, wc = wid & 1;
  const int lr = lane & 15, lk = (lane >> 4) * 8;

  const int srow = tid >> 4;          // 0..15
  const int scol = (tid & 15) * 4;    // 0..60

  f32x4 qr[8], kr[8];
#pragma unroll
  for (int p = 0; p < 8; ++p) {
    int r = p * 16 + srow;
    qr[p] = *(const f32x4*)(Q + (size_t)(rbase + r) * DIM + scol);
    kr[p] = *(const f32x4*)(K + (size_t)(cbase + r) * DIM + scol);
  }

  const f32x4 fzero = {0.f, 0.f, 0.f, 0.f};
  f32x4 acc[4][4];
#pragma unroll
  for (int m = 0; m < 4; ++m)
#pragma unroll
    for (int n = 0; n < 4; ++n) acc[m][n] = fzero;

  for (int kk = 0; kk < DIM / 64; ++kk) {
    __syncthreads();   // previous tile fully consumed
#pragma unroll
    for (int p = 0; p < 8; ++p) {
      int r = p * 16 + srow;
      uint32_t bo = (uint32_t)(r * 128) + (uint32_t)((scol * 2) ^ ((r & 7) << 4));
      u16x4 qh, ql, kh, kl;
      split4(qr[p], qh, ql);
      split4(kr[p], kh, kl);
      *(u16x4*)(sAh + bo) = qh;
      *(u16x4*)(sAl + bo) = ql;
      *(u16x4*)(sBh + bo) = kh;
      *(u16x4*)(sBl + bo) = kl;
    }
    __syncthreads();
    if (kk < DIM / 64 - 1) {   // prefetch next K-tile into regs (hides under MFMA)
#pragma unroll
      for (int p = 0; p < 8; ++p) {
        int r = p * 16 + srow;
        qr[p] = *(const f32x4*)(Q + (size_t)(rbase + r) * DIM + (kk + 1) * 64 + scol);
        kr[p] = *(const f32x4*)(K + (size_t)(cbase + r) * DIM + (kk + 1) * 64 + scol);
      }
    }
#pragma unroll
    for (int kh = 0; kh < 2; ++kh) {
      bf16x8 a_h[4], a_l[4], b_h[4], b_l[4];
#pragma unroll
      for (int m = 0; m < 4; ++m) {
        int row = wr * 64 + m * 16 + lr;
        uint32_t co = (uint32_t)(((kh * 32 + lk) * 2) ^ ((row & 7) << 4));
        a_h[m] = *(const bf16x8*)(sAh + row * 128 + co);
        a_l[m] = *(const bf16x8*)(sAl + row * 128 + co);
      }
#pragma unroll
      for (int n = 0; n < 4; ++n) {
        int row = wc * 64 + n * 16 + lr;
        uint32_t co = (uint32_t)(((kh * 32 + lk) * 2) ^ ((row & 7) << 4));
        b_h[n] = *(const bf16x8*)(sBh + row * 128 + co);
        b_l[n] = *(const bf16x8*)(sBl + row * 128 + co);
      }
#pragma unroll
      for (int m = 0; m < 4; ++m)
#pragma unroll
        for (int n = 0; n < 4; ++n) {
          acc[m][n] = mfma_bf16(a_h[m], b_h[n], acc[m][n]);
          acc[m][n] = mfma_bf16(a_h[m], b_l[n], acc[m][n]);
          acc[m][n] = mfma_bf16(a_l[m], b_h[n], acc[m][n]);
        }
    }
  }

#pragma unroll
  for (int m = 0; m < 4; ++m) {
    int row = rbase + wr * 64 + m * 16 + (lane >> 4) * 4;
#pragma unroll
    for (int n = 0; n < 4; ++n) {
      int col = cbase + wc * 64 + n * 16 + lr;
#pragma unroll
      for (int j = 0; j < 4; ++j)
        S[(size_t)(row + j) * N_K + col] = acc[m][n][j];
    }
  }
}

// ---------------------------------------------------------------------------
// Kernel 2: row softmax in place, one block (256 thr) per row of 4096
// ---------------------------------------------------------------------------
__global__ __launch_bounds__(256) void softmax_kernel(float* __restrict__ P) {
  const int tid = threadIdx.x;
  const int wid = tid >> 6, lane = tid & 63;
  float* p = P + (size_t)blockIdx.x * N_K;

  f32x4 v[4];
  float mx = -3.0e38f;
#pragma unroll
  for (int i = 0; i < 4; ++i) {
    v[i] = *(const f32x4*)(p + i * 1024 + tid * 4);
    mx = fmaxf(mx, fmaxf(fmaxf(v[i][0], v[i][1]), fmaxf(v[i][2], v[i][3])));
  }
#pragma unroll
  for (int o = 32; o > 0; o >>= 1) mx = fmaxf(mx, __shfl_xor(mx, o, 64));
  __shared__ float redM[4];
  __shared__ float redS[4];
  if (lane == 0) redM[wid] = mx;
  __syncthreads();
  mx = fmaxf(fmaxf(redM[0], redM[1]), fmaxf(redM[2], redM[3]));

  float s = 0.f;
#pragma unroll
  for (int i = 0; i < 4; ++i) {
#pragma unroll
    for (int j = 0; j < 4; ++j) {
      v[i][j] = __expf(v[i][j] - mx);
      s += v[i][j];
    }
  }
#pragma unroll
  for (int o = 32; o > 0; o >>= 1) s += __shfl_xor(s, o, 64);
  if (lane == 0) redS[wid] = s;
  __syncthreads();
  s = redS[0] + redS[1] + redS[2] + redS[3];
  const float inv = 1.0f / s;
#pragma unroll
  for (int i = 0; i < 4; ++i) {
    v[i] *= inv;
    *(f32x4*)(p + i * 1024 + tid * 4) = v[i];
  }
}

// ---------------------------------------------------------------------------
// Kernel 3: O = P * V    (bf16 GEMM, fp32 out)
// 128x128 tile over (N rows, D cols), BK=64 along M; 512 threads (8 waves 2x4),
// wave = 64x32 (4x2 frags). V tile transposed into LDS during staging.
// ---------------------------------------------------------------------------
__global__ __launch_bounds__(512, 2) void pv_kernel(const float* __restrict__ P,
                                                    const float* __restrict__ V,
                                                    float* __restrict__ O) {
  __shared__ __align__(16) char sA[16384];   // P tile: 128 rows x 64 k, bf16
  __shared__ __align__(16) char sB[16384];   // V^T tile: 128 cols x 64 k, bf16

  const int tid = threadIdx.x;
  const int rbase = blockIdx.y * 128;   // P rows
  const int cbase = blockIdx.x * 128;   // V cols (D)
  const int lane = tid & 63, wid = tid >> 6;
  const int wr = wid >> 2, wc = wid & 3;   // 2 x 4 wave grid
  const int lr = lane & 15, lk = (lane >> 4) * 8;

  const int a_row = tid >> 4;         // 0..31 (+ p*32)
  const int a_col = (tid & 15) * 4;
  const int b_c = tid & 127;          // V tile column 0..127
  const int b_oct = tid >> 7;         // 0..3

  f32x4 areg[4];
  float breg[4][4];
#pragma unroll
  for (int p = 0; p < 4; ++p) {
    int r = p * 32 + a_row;
    areg[p] = *(const f32x4*)(P + (size_t)(rbase + r) * N_K + a_col);
  }
#pragma unroll
  for (int g = 0; g < 4; ++g) {
    int kr0 = b_oct * 4 + g * 16;
#pragma unroll
    for (int i = 0; i < 4; ++i)
      breg[g][i] = V[(size_t)(kr0 + i) * DIM + cbase + b_c];
  }

  const f32x4 fzero = {0.f, 0.f, 0.f, 0.f};
  f32x4 acc[4][2];
#pragma unroll
  for (int m = 0; m < 4; ++m)
#pragma unroll
    for (int n = 0; n < 2; ++n) acc[m][n] = fzero;

  for (int kk = 0; kk < N_K / 64; ++kk) {
    __syncthreads();
#pragma unroll
    for (int p = 0; p < 4; ++p) {
      int r = p * 32 + a_row;
      uint32_t bo = (uint32_t)(r * 128) + (uint32_t)((a_col * 2) ^ ((r & 7) << 4));
      u16x4 hv;
#pragma unroll
      for (int i = 0; i < 4; ++i) hv[i] = bf16r(areg[p][i]);
      *(u16x4*)(sA + bo) = hv;
    }
#pragma unroll
    for (int g = 0; g < 4; ++g) {
      int kr0 = b_oct * 4 + g * 16;
      uint32_t bo = (uint32_t)(b_c * 128) + (uint32_t)((kr0 * 2) ^ ((b_c & 7) << 4));
      u16x4 hv;
#pragma unroll
      for (int i = 0; i < 4; ++i) hv[i] = bf16r(breg[g][i]);
      *(u16x4*)(sB + bo) = hv;
    }
    __syncthreads();
    if (kk < N_K / 64 - 1) {
#pragma unroll
      for (int p = 0; p < 4; ++p) {
        int r = p * 32 + a_row;
        areg[p] = *(const f32x4*)(P + (size_t)(rbase + r) * N_K + (kk + 1) * 64 + a_col);
      }
#pragma unroll
      for (int g = 0; g < 4; ++g) {
        int kr0 = b_oct * 4 + g * 16;
#pragma unroll
        for (int i = 0; i < 4; ++i)
          breg[g][i] = V[(size_t)((kk + 1) * 64 + kr0 + i) * DIM + cbase + b_c];
      }
    }
#pragma unroll
    for (int kh = 0; kh < 2; ++kh) {
      bf16x8 af[4], bf[2];
#pragma unroll
      for (int m = 0; m < 4; ++m) {
        int row = wr * 64 + m * 16 + lr;
        uint32_t co = (uint32_t)(((kh * 32 + lk) * 2) ^ ((row & 7) << 4));
        af[m] = *(const bf16x8*)(sA + row * 128 + co);
      }
#pragma unroll
      for (int n = 0; n < 2; ++n) {
        int row = wc * 32 + n * 16 + lr;
        uint32_t co = (uint32_t)(((kh * 32 + lk) * 2) ^ ((row & 7) << 4));
        bf[n] = *(const bf16x8*)(sB + row * 128 + co);
      }
#pragma unroll
      for (int m = 0; m < 4; ++m)
#pragma unroll
        for (int n = 0; n < 2; ++n)
          acc[m][n] = mfma_bf16(af[m], bf[n], acc[m][n]);
    }
  }

#pragma unroll
  for (int m = 0; m < 4; ++m) {
    int row = rbase + wr * 64 + m * 16 + (lane >> 4) * 4;
#pragma unroll
    for (int n = 0; n < 2; ++n) {
      int col = cbase + wc * 32 + n * 16 + lr;
#pragma unroll
      for (int j = 0; j < 4; ++j)
        O[(size_t)(row + j) * DIM + col] = acc[m][n][j];
    }
  }
}

extern "C" void kernel_launch(void* const* d_in, const int* in_sizes, int n_in,
                              void* d_out, int out_size, void* d_ws, size_t ws_size,
                              hipStream_t stream) {
  const float* Q = (const float*)d_in[0];
  const float* K = (const float*)d_in[1];
  const float* V = (const float*)d_in[2];
  float* O = (float*)d_out;                       // [4096, 512]
  float* P = O + (size_t)N_Q * DIM;               // [4096, 4096] probs (also scores scratch)

  qk_kernel<<<dim3(N_K / 128, N_Q / 128), 256, 0, stream>>>(Q, K, P);
  softmax_kernel<<<N_Q, 256, 0, stream>>>(P);
  pv_kernel<<<dim3(DIM / 128, N_Q / 128), 512, 0, stream>>>(P, V, O);
}